// Round 11
// baseline (395.251 us; speedup 1.0000x reference)
//
#include <hip/hip_runtime.h>
#include <hip/hip_bf16.h>

// Round 18: attn V-direct-from-L2 (guide common-mistake #7: don't LDS-stage
// L2-resident data). After the XCD swizzle each head's K/V slab is L2-fit
// (FETCH=18.5MB). V's PV A-operand fragment is 16B contiguous along tok ->
// per-lane global_load_dwordx4, no swizzle needed. Removes Vs LDS (32->16KB),
// 8 ds_read_b128/wave/iter and half the gl2lds staging; LDS pipe (~40% of
// the iter wall: 240KB/CU-iter at 128B/cy) is the target. K stays staged
// (4-way reuse), now split across all 4 waves. GEMM/cvt identical to R17.

#define DIM 768
#define NH 12
#define HD 64
#define NTOK 4096
#define WELEM 589824u      // 768*768
#define TELEM 6291456u     // 2*4096*768

typedef short bf16x8 __attribute__((ext_vector_type(8)));
typedef float floatx4 __attribute__((ext_vector_type(4)));
typedef unsigned short us4 __attribute__((ext_vector_type(4)));

__device__ __forceinline__ float bf2f(unsigned short u) {
    union { unsigned int i; float f; } v; v.i = ((unsigned int)u) << 16; return v.f;
}
__device__ __forceinline__ unsigned short f2bf(float f) {
    union { float f; unsigned int i; } v; v.f = f;
    unsigned int r = v.i + 0x7fffu + ((v.i >> 16) & 1u);
    return (unsigned short)(r >> 16);
}
// pack 2 floats -> 2 bf16 in one VGPR (v_cvt_pk_bf16_f32 on gfx950)
__device__ __forceinline__ unsigned int packbf(float a, float b) {
    __hip_bfloat162 h = __float22bfloat162_rn(make_float2(a, b));
    union { __hip_bfloat162 h; unsigned int u; } cv; cv.h = h; return cv.u;
}
__device__ __forceinline__ void gl2lds16(const unsigned short* g, unsigned short* l) {
    __builtin_amdgcn_global_load_lds(
        (const __attribute__((address_space(1))) unsigned int*)g,
        (__attribute__((address_space(3))) unsigned int*)l, 16, 0, 0);
}
__device__ __forceinline__ bf16x8 ld8_f32_to_bf16(const float* p) {
    floatx4 f0 = *(const floatx4*)p;
    floatx4 f1 = *(const floatx4*)(p + 4);
    union { unsigned int u[4]; bf16x8 v; } o;
    o.u[0] = packbf(f0[0], f0[1]);
    o.u[1] = packbf(f0[2], f0[3]);
    o.u[2] = packbf(f1[0], f1[1]);
    o.u[3] = packbf(f1[2], f1[3]);
    return o.v;
}

#if __has_builtin(__builtin_amdgcn_exp2f)
#define EXPFN(x) __builtin_amdgcn_exp2f(x)
#define QSCALE 0.18033688011f   /* 0.125 * log2(e) */
#else
#define EXPFN(x) __expf(x)
#define QSCALE 0.125f
#endif

// ---------------- fused fp32 -> bf16 converter (weights + inputs) ----------
__global__ __launch_bounds__(256) void cvt_all(
    const float* __restrict__ Wq, const float* __restrict__ Wk,
    const float* __restrict__ Wv, const float* __restrict__ Wp,
    const float* __restrict__ q, const float* __restrict__ k,
    const float* __restrict__ v,
    unsigned short* __restrict__ wdst, unsigned short* __restrict__ idst)
{
    size_t i = ((size_t)blockIdx.x * 256 + threadIdx.x) * 8;
    const float* s; size_t off;
    if (i < 4u * WELEM) {
        if (i < WELEM)            { s = Wq; off = i; }
        else if (i < 2u * WELEM)  { s = Wk; off = i - WELEM; }
        else if (i < 3u * WELEM)  { s = Wv; off = i - 2u * WELEM; }
        else                      { s = Wp; off = i - 3u * WELEM; }
        *(bf16x8*)(wdst + i) = ld8_f32_to_bf16(s + off);
    } else {
        size_t j = i - 4u * WELEM;
        if (j < TELEM)            { s = q; off = j; }
        else if (j < 2u * TELEM)  { s = k; off = j - TELEM; }
        else                      { s = v; off = j - 2u * TELEM; }
        *(bf16x8*)(idst + j) = ld8_f32_to_bf16(s + off);
    }
}

// ---------------------------------------------------------------------------
// 128x128 tile GEMM, BK=32, double-buffered LDS (32KiB total).
// Row = 32 elems (64B) = 4 granules of 16B; XOR swizzle with (row>>1)&3.
// (R15/R17 form -- best measured config.)
// ---------------------------------------------------------------------------
template <int A_IS_BF16>
__device__ __forceinline__ void stage32(
    const void* __restrict__ Av, const unsigned short* __restrict__ W,
    unsigned short* Asb, unsigned short* Bsb,
    int m0, int n0, int k0, int w, int l)
{
    const int ro = l >> 2;   // 0..15
    const int gs = l & 3;    // LDS granule position
#pragma unroll
    for (int q = 0; q < 2; q++) {
        int rbase = w * 32 + q * 16;
        int row = rbase + ro;
        int col = ((gs ^ ((row >> 1) & 3)) * 8);   // pre-swizzled global source
        if (A_IS_BF16) {
            gl2lds16((const unsigned short*)Av + (size_t)(m0 + row) * DIM + k0 + col,
                     Asb + rbase * 32);
        } else {
            bf16x8 a = ld8_f32_to_bf16((const float*)Av + (size_t)(m0 + row) * DIM + k0 + col);
            *(bf16x8*)(Asb + row * 32 + gs * 8) = a;
        }
        gl2lds16(W + (size_t)(n0 + row) * DIM + k0 + col, Bsb + rbase * 32);
    }
}

template <int A_IS_BF16>
__device__ __forceinline__ void gemm128(
    const void* __restrict__ Av, const unsigned short* __restrict__ W,
    const float* __restrict__ bias, void* __restrict__ Cv,
    int has_bias, int do_gelu, int trans, int out_f32)
{
    __shared__ unsigned short As[2][128 * 32];
    __shared__ unsigned short Bs[2][128 * 32];
    const int m0 = blockIdx.x * 128, n0 = blockIdx.y * 128;
    const int tid = threadIdx.x;
    const int w = tid >> 6, l = tid & 63;
    const int g = l >> 4, r16 = l & 15;
    const int wm = w >> 1, wn = w & 1;
    const int NKT = DIM / 32;   // 24

    // fragment LDS offsets (swizzled read side)
    int aoff[4], boff[4];
#pragma unroll
    for (int i = 0; i < 4; i++) {
        int row = wm * 64 + i * 16 + r16;
        aoff[i] = row * 32 + ((g ^ ((row >> 1) & 3)) * 8);
    }
#pragma unroll
    for (int j = 0; j < 4; j++) {
        int row = wn * 64 + j * 16 + r16;
        boff[j] = row * 32 + ((g ^ ((row >> 1) & 3)) * 8);
    }

    floatx4 acc[4][4];
#pragma unroll
    for (int i = 0; i < 4; i++)
#pragma unroll
        for (int j = 0; j < 4; j++) acc[i][j] = (floatx4){0.f, 0.f, 0.f, 0.f};

    // prologue: stage tile 0 into buffer 0
    stage32<A_IS_BF16>(Av, W, As[0], Bs[0], m0, n0, 0, w, l);
    __syncthreads();

    for (int kt = 0; kt < NKT; kt++) {
        const int cur = kt & 1;

        // prefetch tile kt+1 into the other buffer (issued before compute)
        if (kt + 1 < NKT)
            stage32<A_IS_BF16>(Av, W, As[cur ^ 1], Bs[cur ^ 1],
                               m0, n0, (kt + 1) * 32, w, l);

        bf16x8 af[4], bfr[4];
#pragma unroll
        for (int i = 0; i < 4; i++)
            af[i] = *(const bf16x8*)(As[cur] + aoff[i]);
#pragma unroll
        for (int j = 0; j < 4; j++)
            bfr[j] = *(const bf16x8*)(Bs[cur] + boff[j]);
#pragma unroll
        for (int i = 0; i < 4; i++)
#pragma unroll
            for (int j = 0; j < 4; j++)
                acc[i][j] = __builtin_amdgcn_mfma_f32_16x16x32_bf16(af[i], bfr[j], acc[i][j], 0, 0, 0);

        // one barrier/iter: drains this iter's prefetch (issued ~compute-length
        // ago) and orders the buffer swap.
        __syncthreads();
    }

    if (trans) {
        unsigned short* C = (unsigned short*)Cv;
#pragma unroll
        for (int i = 0; i < 4; i++) {
            int m = m0 + wm * 64 + i * 16 + g * 4;
            int b = m >> 12, tloc = m & 4095;
#pragma unroll
            for (int j = 0; j < 4; j++) {
                int n = n0 + wn * 64 + j * 16 + r16;
                int h = n >> 6, d = n & 63;
                union { unsigned int u[2]; us4 v; } pk;
                pk.u[0] = packbf(acc[i][j][0], acc[i][j][1]);
                pk.u[1] = packbf(acc[i][j][2], acc[i][j][3]);
                *(us4*)(C + ((size_t)(b * NH + h) * 64 + d) * NTOK + tloc) = pk.v;
            }
        }
    } else {
#pragma unroll
        for (int i = 0; i < 4; i++)
#pragma unroll
            for (int j = 0; j < 4; j++) {
                int n = n0 + wn * 64 + j * 16 + r16;
                float bv = has_bias ? bias[n] : 0.f;
#pragma unroll
                for (int r = 0; r < 4; r++) {
                    int m = m0 + wm * 64 + i * 16 + g * 4 + r;
                    float v = acc[i][j][r] + bv;
                    if (do_gelu) v = 0.5f * v * (1.f + erff(v * 0.70710678118f));
                    if (out_f32) ((float*)Cv)[(size_t)m * DIM + n] = v;
                    else ((unsigned short*)Cv)[(size_t)m * DIM + n] = f2bf(v);
                }
            }
    }
}

template <int A_IS_BF16>
__global__ __launch_bounds__(256) void qkv_gemm(
    const void* __restrict__ q_in, const void* __restrict__ k_in,
    const void* __restrict__ v_in,
    const unsigned short* __restrict__ Wq, const unsigned short* __restrict__ Wk,
    const unsigned short* __restrict__ Wv, const float* __restrict__ bk,
    unsigned short* __restrict__ Qo, unsigned short* __restrict__ Ko,
    unsigned short* __restrict__ Vto)
{
    int z = blockIdx.z;
    const void* A = (z == 0) ? q_in : (z == 1) ? k_in : v_in;
    const unsigned short* W = (z == 0) ? Wq : (z == 1) ? Wk : Wv;
    unsigned short* C = (z == 0) ? Qo : (z == 1) ? Ko : Vto;
    gemm128<A_IS_BF16>(A, W, bk, C, z == 1, z == 1, z == 2, 0);
}

__global__ __launch_bounds__(256) void out_gemm(
    const unsigned short* __restrict__ X, const unsigned short* __restrict__ Wp,
    const float* __restrict__ bp, float* __restrict__ out)
{
    gemm128<1>(X, Wp, bp, out, 1, 0, 0, 1);
}

// ---------------------------------------------------------------------------
// Flash attention R18: XCD swizzle, 4 waves x 32 q-rows, QK-hoist,
// lsum-via-MFMA, wave-parity stagger. V read DIRECTLY from global (L2) as
// per-lane bf16x8; only K staged in LDS (16KB, split across all 4 waves).
// ---------------------------------------------------------------------------
__device__ __forceinline__ int swzf(int R) { return (R & 7) ^ ((R >> 2) & 6); }

__global__ __launch_bounds__(256, 3) void attn_kernel(
    const unsigned short* __restrict__ Q, const unsigned short* __restrict__ K,
    const unsigned short* __restrict__ Vt, unsigned short* __restrict__ X)
{
    __shared__ unsigned short Ks[2][64 * 64];
    const int lid = blockIdx.y * gridDim.x + blockIdx.x;   // 0..767
    const int lid2 = (lid & 7) * 96 + (lid >> 3);
    const int qt = lid2 & 31, bh = lid2 >> 5;
    const int b = bh / NH, h = bh % NH;
    const int tid = threadIdx.x;
    const int w = tid >> 6, l = tid & 63;
    const int g = l >> 4, r16 = l & 15;
    const int tokbase = b * NTOK;

    bf16x8 qfr[2][2];
#pragma unroll
    for (int qfi = 0; qfi < 2; qfi++) {
        int qrow = tokbase + qt * 128 + w * 32 + qfi * 16 + r16;
#pragma unroll
        for (int kk = 0; kk < 2; kk++) {
            bf16x8 t = *(const bf16x8*)(Q + (size_t)qrow * DIM + h * HD + kk * 32 + g * 8);
#pragma unroll
            for (int j = 0; j < 8; j++)
                t[j] = (short)f2bf(bf2f((unsigned short)t[j]) * QSCALE);
            qfr[qfi][kk] = t;
        }
    }

    bf16x8 ones;
#pragma unroll
    for (int j = 0; j < 8; j++) ones[j] = (short)0x3F80;

    // K fragment LDS offsets (swizzled, unchanged)
    int koff[4][2];
#pragma unroll
    for (int ct = 0; ct < 4; ct++) {
        int krow = (ct >> 1) * 32 + (r16 >> 2) * 8 + (ct & 1) * 4 + (r16 & 3);
#pragma unroll
        for (int kk = 0; kk < 2; kk++)
            koff[ct][kk] = krow * 64 + (((kk * 4 + g) ^ swzf(krow)) * 8);
    }

    // V global fragment offsets: row = d (dt*16+r16) along NTOK-stride,
    // 16B contiguous along tok. No swizzle, no LDS.
    const unsigned short* Vbase = Vt + (size_t)bh * 64 * NTOK;
    int vgoff[4][2];
#pragma unroll
    for (int dt = 0; dt < 4; dt++)
#pragma unroll
        for (int c = 0; c < 2; c++)
            vgoff[dt][c] = (dt * 16 + r16) * NTOK + (c * 4 + g) * 8;

    // K staging: each wave stages quarter w (16 rows) = 2 gl2lds16.
    int soff[2];
    const int srl = l >> 3, scc = l & 7;
#pragma unroll
    for (int i = 0; i < 2; i++) {
        int row = w * 16 + i * 8 + srl;
        soff[i] = row * DIM + ((scc ^ swzf(row)) * 8);
    }
    const unsigned short* Kbase = K + (size_t)tokbase * DIM + h * HD;

    floatx4 o[2][4];
#pragma unroll
    for (int qfi = 0; qfi < 2; qfi++)
#pragma unroll
        for (int dt = 0; dt < 4; dt++) o[qfi][dt] = (floatx4){0.f, 0.f, 0.f, 0.f};
    floatx4 lsA = (floatx4){0.f, 0.f, 0.f, 0.f};
    floatx4 lsB = (floatx4){0.f, 0.f, 0.f, 0.f};

    // prologue: stage K tile 0 into buffer 0
    {
        unsigned short* dst = Ks[0] + w * 1024;
#pragma unroll
        for (int i = 0; i < 2; i++) gl2lds16(Kbase + soff[i], dst + i * 512);
    }

    for (int kt = 0; kt < NTOK / 64; kt++) {
        const int cur = kt & 1;
        __syncthreads();   // drains gl2lds -> K tile kt visible to block

        // V direct loads for tile kt: issue FIRST (L2 latency hides under
        // QK MFMA + exp VALU, ~600cy before first use in PV).
        bf16x8 vr[4][2];
        const unsigned short* Vkt = Vbase + kt * 64;
#pragma unroll
        for (int dt = 0; dt < 4; dt++)
#pragma unroll
            for (int c = 0; c < 2; c++)
                vr[dt][c] = *(const bf16x8*)(Vkt + vgoff[dt][c]);

        // K fragment reads from LDS
        bf16x8 kr[4][2];
#pragma unroll
        for (int ct = 0; ct < 4; ct++)
#pragma unroll
            for (int kk = 0; kk < 2; kk++)
                kr[ct][kk] = *(const bf16x8*)(Ks[cur] + koff[ct][kk]);

        // prefetch K tile kt+1 into the other buffer
        if (kt + 1 < NTOK / 64) {
            const unsigned short* p = Kbase + (size_t)(kt + 1) * 64 * DIM;
            unsigned short* dst = Ks[cur ^ 1] + w * 1024;
#pragma unroll
            for (int i = 0; i < 2; i++) gl2lds16(p + soff[i], dst + i * 512);
        }

        // QK^T for BOTH q-subtiles up front (MFMAs retire under exp VALU).
        floatx4 s0[4], s1[4];
#pragma unroll
        for (int ct = 0; ct < 4; ct++) {
            floatx4 zz = (floatx4){0.f, 0.f, 0.f, 0.f};
            zz = __builtin_amdgcn_mfma_f32_16x16x32_bf16(kr[ct][0], qfr[0][0], zz, 0, 0, 0);
            s0[ct] = __builtin_amdgcn_mfma_f32_16x16x32_bf16(kr[ct][1], qfr[0][1], zz, 0, 0, 0);
        }
#pragma unroll
        for (int ct = 0; ct < 4; ct++) {
            floatx4 zz = (floatx4){0.f, 0.f, 0.f, 0.f};
            zz = __builtin_amdgcn_mfma_f32_16x16x32_bf16(kr[ct][0], qfr[1][0], zz, 0, 0, 0);
            s1[ct] = __builtin_amdgcn_mfma_f32_16x16x32_bf16(kr[ct][1], qfr[1][1], zz, 0, 0, 0);
        }

        auto phase = [&](floatx4* s, floatx4* oo, floatx4& ls) {
            unsigned int pk[4][2];
#pragma unroll
            for (int ct = 0; ct < 4; ct++) {
                float p0 = EXPFN(s[ct][0]);
                float p1 = EXPFN(s[ct][1]);
                float p2 = EXPFN(s[ct][2]);
                float p3 = EXPFN(s[ct][3]);
                pk[ct][0] = packbf(p0, p1);
                pk[ct][1] = packbf(p2, p3);
            }
#pragma unroll
            for (int c = 0; c < 2; c++) {
                union { unsigned int u[4]; bf16x8 v; } bf;
                bf.u[0] = pk[2 * c][0]; bf.u[1] = pk[2 * c][1];
                bf.u[2] = pk[2 * c + 1][0]; bf.u[3] = pk[2 * c + 1][1];
#pragma unroll
                for (int dt = 0; dt < 4; dt++)
                    oo[dt] = __builtin_amdgcn_mfma_f32_16x16x32_bf16(vr[dt][c], bf.v, oo[dt], 0, 0, 0);
                ls = __builtin_amdgcn_mfma_f32_16x16x32_bf16(ones, bf.v, ls, 0, 0, 0);
            }
        };
        // wave-parity stagger (kept from R17)
        if (w & 1) {
            phase(s1, o[1], lsB);
            phase(s0, o[0], lsA);
        } else {
            phase(s0, o[0], lsA);
            phase(s1, o[1], lsB);
        }
    }

#pragma unroll
    for (int qfi = 0; qfi < 2; qfi++) {
        float inv = 1.f / (qfi ? lsB[0] : lsA[0]);
        int tok = tokbase + qt * 128 + w * 32 + qfi * 16 + r16;
#pragma unroll
        for (int dt = 0; dt < 4; dt++) {
            union { unsigned int u[2]; us4 v; } pkv;
            pkv.u[0] = packbf(o[qfi][dt][0] * inv, o[qfi][dt][1] * inv);
            pkv.u[1] = packbf(o[qfi][dt][2] * inv, o[qfi][dt][3] * inv);
            *(us4*)(X + (size_t)tok * DIM + h * HD + dt * 16 + g * 4) = pkv.v;
        }
    }
}

extern "C" void kernel_launch(void* const* d_in, const int* in_sizes, int n_in,
                              void* d_out, int out_size, void* d_ws, size_t ws_size,
                              hipStream_t stream) {
    const float* query = (const float*)d_in[0];
    const float* key   = (const float*)d_in[1];
    const float* value = (const float*)d_in[2];
    const float* Wq    = (const float*)d_in[3];
    const float* Wk    = (const float*)d_in[4];
    const float* bk    = (const float*)d_in[5];
    const float* Wv    = (const float*)d_in[6];
    const float* Wp    = (const float*)d_in[7];
    const float* bp    = (const float*)d_in[8];
    float* out = (float*)d_out;

    unsigned short* ws = (unsigned short*)d_ws;
    unsigned short* Wqb = ws;
    unsigned short* Wkb = Wqb + WELEM;
    unsigned short* Wvb = Wkb + WELEM;
    unsigned short* Wpb = Wvb + WELEM;
    unsigned short* Qp  = Wpb + WELEM;
    unsigned short* Kp  = Qp + TELEM;
    unsigned short* Vtp = Kp + TELEM;
    unsigned short* Xp  = Vtp + TELEM;
    unsigned short* Qbf = Xp + TELEM;
    unsigned short* Kbf = Qbf + TELEM;
    unsigned short* Vbf = Kbf + TELEM;

    const size_t base_b = ((size_t)4 * WELEM + 4 * TELEM) * 2;
    const size_t cvt_b  = (size_t)3 * TELEM * 2;
    const bool cvt_ok = ws_size >= base_b + cvt_b;

    if (cvt_ok) {
        cvt_all<<<dim3((4 * WELEM + 3 * TELEM) / 8 / 256), 256, 0, stream>>>(
            Wq, Wk, Wv, Wp, query, key, value, Wqb, Qbf);
        qkv_gemm<1><<<dim3(64, 6, 3), 256, 0, stream>>>(Qbf, Kbf, Vbf, Wqb, Wkb, Wvb, bk, Qp, Kp, Vtp);
    } else {
        cvt_all<<<dim3(4 * WELEM / 8 / 256), 256, 0, stream>>>(
            Wq, Wk, Wv, Wp, query, key, value, Wqb, Qbf);
        qkv_gemm<0><<<dim3(64, 6, 3), 256, 0, stream>>>(query, key, value, Wqb, Wkb, Wvb, bk, Qp, Kp, Vtp);
    }
    attn_kernel<<<dim3(32, 24), 256, 0, stream>>>(Qp, Kp, Vtp, Xp);
    out_gemm<<<dim3(64, 6), 256, 0, stream>>>(Xp, Wpb, bp, out);
}

// Round 12
// 335.365 us; speedup vs baseline: 1.1786x; 1.1786x over previous
//
#include <hip/hip_runtime.h>
#include <hip/hip_bf16.h>

// Round 19: (a) REVERT R18's V-direct (225us: scattered per-lane V loads,
// exposed L2 latency). Vs LDS staging restored. (b) attn geometry: 2 waves x
// 32 q-rows per block (128 thr), qt-tile 64 rows, grid 64x24=1536. Same
// per-wave body as R17; LDS 32KB/block -> 5 blocks/CU = 5 INDEPENDENT
// barrier groups per CU (vs 3 correlated 4-wave groups). Mechanism: the
// irreducible exp-VALU (~330cy/wave-iter, VALUBusy 57%) can only overlap
// MFMA/LDS of waves in OTHER barrier groups; more groups = finer phase
// interleave. XCD swizzle rescaled (1536=8x192, 3 heads/XCD unchanged).
// GEMM/cvt identical to R17 (best total 304.2).

#define DIM 768
#define NH 12
#define HD 64
#define NTOK 4096
#define WELEM 589824u      // 768*768
#define TELEM 6291456u     // 2*4096*768

typedef short bf16x8 __attribute__((ext_vector_type(8)));
typedef float floatx4 __attribute__((ext_vector_type(4)));
typedef unsigned short us4 __attribute__((ext_vector_type(4)));

__device__ __forceinline__ float bf2f(unsigned short u) {
    union { unsigned int i; float f; } v; v.i = ((unsigned int)u) << 16; return v.f;
}
__device__ __forceinline__ unsigned short f2bf(float f) {
    union { float f; unsigned int i; } v; v.f = f;
    unsigned int r = v.i + 0x7fffu + ((v.i >> 16) & 1u);
    return (unsigned short)(r >> 16);
}
// pack 2 floats -> 2 bf16 in one VGPR (v_cvt_pk_bf16_f32 on gfx950)
__device__ __forceinline__ unsigned int packbf(float a, float b) {
    __hip_bfloat162 h = __float22bfloat162_rn(make_float2(a, b));
    union { __hip_bfloat162 h; unsigned int u; } cv; cv.h = h; return cv.u;
}
__device__ __forceinline__ void gl2lds16(const unsigned short* g, unsigned short* l) {
    __builtin_amdgcn_global_load_lds(
        (const __attribute__((address_space(1))) unsigned int*)g,
        (__attribute__((address_space(3))) unsigned int*)l, 16, 0, 0);
}
__device__ __forceinline__ bf16x8 ld8_f32_to_bf16(const float* p) {
    floatx4 f0 = *(const floatx4*)p;
    floatx4 f1 = *(const floatx4*)(p + 4);
    union { unsigned int u[4]; bf16x8 v; } o;
    o.u[0] = packbf(f0[0], f0[1]);
    o.u[1] = packbf(f0[2], f0[3]);
    o.u[2] = packbf(f1[0], f1[1]);
    o.u[3] = packbf(f1[2], f1[3]);
    return o.v;
}

#if __has_builtin(__builtin_amdgcn_exp2f)
#define EXPFN(x) __builtin_amdgcn_exp2f(x)
#define QSCALE 0.18033688011f   /* 0.125 * log2(e) */
#else
#define EXPFN(x) __expf(x)
#define QSCALE 0.125f
#endif

// ---------------- fused fp32 -> bf16 converter (weights + inputs) ----------
__global__ __launch_bounds__(256) void cvt_all(
    const float* __restrict__ Wq, const float* __restrict__ Wk,
    const float* __restrict__ Wv, const float* __restrict__ Wp,
    const float* __restrict__ q, const float* __restrict__ k,
    const float* __restrict__ v,
    unsigned short* __restrict__ wdst, unsigned short* __restrict__ idst)
{
    size_t i = ((size_t)blockIdx.x * 256 + threadIdx.x) * 8;
    const float* s; size_t off;
    if (i < 4u * WELEM) {
        if (i < WELEM)            { s = Wq; off = i; }
        else if (i < 2u * WELEM)  { s = Wk; off = i - WELEM; }
        else if (i < 3u * WELEM)  { s = Wv; off = i - 2u * WELEM; }
        else                      { s = Wp; off = i - 3u * WELEM; }
        *(bf16x8*)(wdst + i) = ld8_f32_to_bf16(s + off);
    } else {
        size_t j = i - 4u * WELEM;
        if (j < TELEM)            { s = q; off = j; }
        else if (j < 2u * TELEM)  { s = k; off = j - TELEM; }
        else                      { s = v; off = j - 2u * TELEM; }
        *(bf16x8*)(idst + j) = ld8_f32_to_bf16(s + off);
    }
}

// ---------------------------------------------------------------------------
// 128x128 tile GEMM, BK=32, double-buffered LDS (32KiB total).
// Row = 32 elems (64B) = 4 granules of 16B; XOR swizzle with (row>>1)&3.
// (R15/R17 form -- best measured config.)
// ---------------------------------------------------------------------------
template <int A_IS_BF16>
__device__ __forceinline__ void stage32(
    const void* __restrict__ Av, const unsigned short* __restrict__ W,
    unsigned short* Asb, unsigned short* Bsb,
    int m0, int n0, int k0, int w, int l)
{
    const int ro = l >> 2;   // 0..15
    const int gs = l & 3;    // LDS granule position
#pragma unroll
    for (int q = 0; q < 2; q++) {
        int rbase = w * 32 + q * 16;
        int row = rbase + ro;
        int col = ((gs ^ ((row >> 1) & 3)) * 8);   // pre-swizzled global source
        if (A_IS_BF16) {
            gl2lds16((const unsigned short*)Av + (size_t)(m0 + row) * DIM + k0 + col,
                     Asb + rbase * 32);
        } else {
            bf16x8 a = ld8_f32_to_bf16((const float*)Av + (size_t)(m0 + row) * DIM + k0 + col);
            *(bf16x8*)(Asb + row * 32 + gs * 8) = a;
        }
        gl2lds16(W + (size_t)(n0 + row) * DIM + k0 + col, Bsb + rbase * 32);
    }
}

template <int A_IS_BF16>
__device__ __forceinline__ void gemm128(
    const void* __restrict__ Av, const unsigned short* __restrict__ W,
    const float* __restrict__ bias, void* __restrict__ Cv,
    int has_bias, int do_gelu, int trans, int out_f32)
{
    __shared__ unsigned short As[2][128 * 32];
    __shared__ unsigned short Bs[2][128 * 32];
    const int m0 = blockIdx.x * 128, n0 = blockIdx.y * 128;
    const int tid = threadIdx.x;
    const int w = tid >> 6, l = tid & 63;
    const int g = l >> 4, r16 = l & 15;
    const int wm = w >> 1, wn = w & 1;
    const int NKT = DIM / 32;   // 24

    // fragment LDS offsets (swizzled read side)
    int aoff[4], boff[4];
#pragma unroll
    for (int i = 0; i < 4; i++) {
        int row = wm * 64 + i * 16 + r16;
        aoff[i] = row * 32 + ((g ^ ((row >> 1) & 3)) * 8);
    }
#pragma unroll
    for (int j = 0; j < 4; j++) {
        int row = wn * 64 + j * 16 + r16;
        boff[j] = row * 32 + ((g ^ ((row >> 1) & 3)) * 8);
    }

    floatx4 acc[4][4];
#pragma unroll
    for (int i = 0; i < 4; i++)
#pragma unroll
        for (int j = 0; j < 4; j++) acc[i][j] = (floatx4){0.f, 0.f, 0.f, 0.f};

    // prologue: stage tile 0 into buffer 0
    stage32<A_IS_BF16>(Av, W, As[0], Bs[0], m0, n0, 0, w, l);
    __syncthreads();

    for (int kt = 0; kt < NKT; kt++) {
        const int cur = kt & 1;

        // prefetch tile kt+1 into the other buffer (issued before compute)
        if (kt + 1 < NKT)
            stage32<A_IS_BF16>(Av, W, As[cur ^ 1], Bs[cur ^ 1],
                               m0, n0, (kt + 1) * 32, w, l);

        bf16x8 af[4], bfr[4];
#pragma unroll
        for (int i = 0; i < 4; i++)
            af[i] = *(const bf16x8*)(As[cur] + aoff[i]);
#pragma unroll
        for (int j = 0; j < 4; j++)
            bfr[j] = *(const bf16x8*)(Bs[cur] + boff[j]);
#pragma unroll
        for (int i = 0; i < 4; i++)
#pragma unroll
            for (int j = 0; j < 4; j++)
                acc[i][j] = __builtin_amdgcn_mfma_f32_16x16x32_bf16(af[i], bfr[j], acc[i][j], 0, 0, 0);

        // one barrier/iter: drains this iter's prefetch (issued ~compute-length
        // ago) and orders the buffer swap.
        __syncthreads();
    }

    if (trans) {
        unsigned short* C = (unsigned short*)Cv;
#pragma unroll
        for (int i = 0; i < 4; i++) {
            int m = m0 + wm * 64 + i * 16 + g * 4;
            int b = m >> 12, tloc = m & 4095;
#pragma unroll
            for (int j = 0; j < 4; j++) {
                int n = n0 + wn * 64 + j * 16 + r16;
                int h = n >> 6, d = n & 63;
                union { unsigned int u[2]; us4 v; } pk;
                pk.u[0] = packbf(acc[i][j][0], acc[i][j][1]);
                pk.u[1] = packbf(acc[i][j][2], acc[i][j][3]);
                *(us4*)(C + ((size_t)(b * NH + h) * 64 + d) * NTOK + tloc) = pk.v;
            }
        }
    } else {
#pragma unroll
        for (int i = 0; i < 4; i++)
#pragma unroll
            for (int j = 0; j < 4; j++) {
                int n = n0 + wn * 64 + j * 16 + r16;
                float bv = has_bias ? bias[n] : 0.f;
#pragma unroll
                for (int r = 0; r < 4; r++) {
                    int m = m0 + wm * 64 + i * 16 + g * 4 + r;
                    float v = acc[i][j][r] + bv;
                    if (do_gelu) v = 0.5f * v * (1.f + erff(v * 0.70710678118f));
                    if (out_f32) ((float*)Cv)[(size_t)m * DIM + n] = v;
                    else ((unsigned short*)Cv)[(size_t)m * DIM + n] = f2bf(v);
                }
            }
    }
}

template <int A_IS_BF16>
__global__ __launch_bounds__(256) void qkv_gemm(
    const void* __restrict__ q_in, const void* __restrict__ k_in,
    const void* __restrict__ v_in,
    const unsigned short* __restrict__ Wq, const unsigned short* __restrict__ Wk,
    const unsigned short* __restrict__ Wv, const float* __restrict__ bk,
    unsigned short* __restrict__ Qo, unsigned short* __restrict__ Ko,
    unsigned short* __restrict__ Vto)
{
    int z = blockIdx.z;
    const void* A = (z == 0) ? q_in : (z == 1) ? k_in : v_in;
    const unsigned short* W = (z == 0) ? Wq : (z == 1) ? Wk : Wv;
    unsigned short* C = (z == 0) ? Qo : (z == 1) ? Ko : Vto;
    gemm128<A_IS_BF16>(A, W, bk, C, z == 1, z == 1, z == 2, 0);
}

__global__ __launch_bounds__(256) void out_gemm(
    const unsigned short* __restrict__ X, const unsigned short* __restrict__ Wp,
    const float* __restrict__ bp, float* __restrict__ out)
{
    gemm128<1>(X, Wp, bp, out, 1, 0, 0, 1);
}

// ---------------------------------------------------------------------------
// Flash attention R19: 2 waves x 32 q-rows per block (128 thr), qt-tile 64,
// grid 64x24=1536, 5 blocks/CU = 5 independent barrier groups. Per-wave body
// identical to R17 (XCD swizzle, QK-hoist, lsum-via-MFMA, parity stagger).
// Staging: wave 0 -> K tile, wave 1 -> V tile (8 gl2lds each).
// ---------------------------------------------------------------------------
__device__ __forceinline__ int swzf(int R) { return (R & 7) ^ ((R >> 2) & 6); }

__global__ __launch_bounds__(128, 2) void attn_kernel(
    const unsigned short* __restrict__ Q, const unsigned short* __restrict__ K,
    const unsigned short* __restrict__ Vt, unsigned short* __restrict__ X)
{
    __shared__ unsigned short Ks[2][64 * 64];
    __shared__ unsigned short Vs[2][64 * 64];
    // XCD swizzle: 1536 blocks = 8 XCDs x 192; each XCD owns 192 consecutive
    // logical blocks = 3 full heads x 64 qt-tiles; K/V slab 3MB fits 4MB L2.
    const int lid = blockIdx.y * gridDim.x + blockIdx.x;   // 0..1535
    const int lid2 = (lid & 7) * 192 + (lid >> 3);
    const int qt = lid2 & 63, bh = lid2 >> 6;
    const int b = bh / NH, h = bh % NH;
    const int tid = threadIdx.x;
    const int w = tid >> 6, l = tid & 63;   // w in {0,1}
    const int g = l >> 4, r16 = l & 15;
    const int tokbase = b * NTOK;

    // per-wave Q fragments: wave w owns rows qt*64 + w*32 .. +31  (2 x 16)
    bf16x8 qfr[2][2];
#pragma unroll
    for (int qfi = 0; qfi < 2; qfi++) {
        int qrow = tokbase + qt * 64 + w * 32 + qfi * 16 + r16;
#pragma unroll
        for (int kk = 0; kk < 2; kk++) {
            bf16x8 t = *(const bf16x8*)(Q + (size_t)qrow * DIM + h * HD + kk * 32 + g * 8);
#pragma unroll
            for (int j = 0; j < 8; j++)
                t[j] = (short)f2bf(bf2f((unsigned short)t[j]) * QSCALE);
            qfr[qfi][kk] = t;
        }
    }

    bf16x8 ones;
#pragma unroll
    for (int j = 0; j < 8; j++) ones[j] = (short)0x3F80;

    int koff[4][2], voff[4][2];
#pragma unroll
    for (int ct = 0; ct < 4; ct++) {
        int krow = (ct >> 1) * 32 + (r16 >> 2) * 8 + (ct & 1) * 4 + (r16 & 3);
#pragma unroll
        for (int kk = 0; kk < 2; kk++)
            koff[ct][kk] = krow * 64 + (((kk * 4 + g) ^ swzf(krow)) * 8);
    }
#pragma unroll
    for (int dt = 0; dt < 4; dt++) {
        int vrow = dt * 16 + r16;
#pragma unroll
        for (int c = 0; c < 2; c++)
            voff[dt][c] = vrow * 64 + (((c * 4 + g) ^ swzf(vrow)) * 8);
    }

    // staging: wave 0 -> K tile, wave 1 -> V tile. 8 chunks of 8 rows each.
    const int kv = w;
    int soff[8];
    const int srl = l >> 3, scc = l & 7;
    const int sstride = (kv == 0) ? DIM : NTOK;
#pragma unroll
    for (int i = 0; i < 8; i++) {
        int row = i * 8 + srl;
        soff[i] = row * sstride + ((scc ^ swzf(row)) * 8);
    }
    const unsigned short* Kbase = K + (size_t)tokbase * DIM + h * HD;
    const unsigned short* Vbase = Vt + (size_t)bh * 64 * NTOK;

    floatx4 o[2][4];
#pragma unroll
    for (int qfi = 0; qfi < 2; qfi++)
#pragma unroll
        for (int dt = 0; dt < 4; dt++) o[qfi][dt] = (floatx4){0.f, 0.f, 0.f, 0.f};
    floatx4 lsA = (floatx4){0.f, 0.f, 0.f, 0.f};
    floatx4 lsB = (floatx4){0.f, 0.f, 0.f, 0.f};

    // prologue: stage tile 0 into buffer 0
    {
        const unsigned short* p = (kv == 0) ? Kbase : Vbase;
        unsigned short* dst = (kv == 0) ? Ks[0] : Vs[0];
#pragma unroll
        for (int i = 0; i < 8; i++) gl2lds16(p + soff[i], dst + i * 512);
    }

    for (int kt = 0; kt < NTOK / 64; kt++) {
        const int cur = kt & 1;
        __syncthreads();   // drains gl2lds -> tile kt visible to block

        // consume tile kt: fragment reads FIRST (program order before next issue)
        bf16x8 kr[4][2], vr[4][2];
#pragma unroll
        for (int ct = 0; ct < 4; ct++)
#pragma unroll
            for (int kk = 0; kk < 2; kk++)
                kr[ct][kk] = *(const bf16x8*)(Ks[cur] + koff[ct][kk]);
#pragma unroll
        for (int dt = 0; dt < 4; dt++)
#pragma unroll
            for (int c = 0; c < 2; c++)
                vr[dt][c] = *(const bf16x8*)(Vs[cur] + voff[dt][c]);

        // prefetch tile kt+1 into the other buffer (hidden behind compute)
        if (kt + 1 < NTOK / 64) {
            int keyg = (kt + 1) * 64;
            const unsigned short* p = (kv == 0) ? (Kbase + (size_t)keyg * DIM)
                                                : (Vbase + keyg);
            unsigned short* dst = (kv == 0) ? Ks[cur ^ 1] : Vs[cur ^ 1];
#pragma unroll
            for (int i = 0; i < 8; i++) gl2lds16(p + soff[i], dst + i * 512);
        }

        // QK^T for BOTH q-subtiles up front (MFMAs retire under exp VALU).
        floatx4 s0[4], s1[4];
#pragma unroll
        for (int ct = 0; ct < 4; ct++) {
            floatx4 zz = (floatx4){0.f, 0.f, 0.f, 0.f};
            zz = __builtin_amdgcn_mfma_f32_16x16x32_bf16(kr[ct][0], qfr[0][0], zz, 0, 0, 0);
            s0[ct] = __builtin_amdgcn_mfma_f32_16x16x32_bf16(kr[ct][1], qfr[0][1], zz, 0, 0, 0);
        }
#pragma unroll
        for (int ct = 0; ct < 4; ct++) {
            floatx4 zz = (floatx4){0.f, 0.f, 0.f, 0.f};
            zz = __builtin_amdgcn_mfma_f32_16x16x32_bf16(kr[ct][0], qfr[1][0], zz, 0, 0, 0);
            s1[ct] = __builtin_amdgcn_mfma_f32_16x16x32_bf16(kr[ct][1], qfr[1][1], zz, 0, 0, 0);
        }

        auto phase = [&](floatx4* s, floatx4* oo, floatx4& ls) {
            unsigned int pk[4][2];
#pragma unroll
            for (int ct = 0; ct < 4; ct++) {
                float p0 = EXPFN(s[ct][0]);
                float p1 = EXPFN(s[ct][1]);
                float p2 = EXPFN(s[ct][2]);
                float p3 = EXPFN(s[ct][3]);
                pk[ct][0] = packbf(p0, p1);
                pk[ct][1] = packbf(p2, p3);
            }
#pragma unroll
            for (int c = 0; c < 2; c++) {
                union { unsigned int u[4]; bf16x8 v; } bf;
                bf.u[0] = pk[2 * c][0]; bf.u[1] = pk[2 * c][1];
                bf.u[2] = pk[2 * c + 1][0]; bf.u[3] = pk[2 * c + 1][1];
#pragma unroll
                for (int dt = 0; dt < 4; dt++)
                    oo[dt] = __builtin_amdgcn_mfma_f32_16x16x32_bf16(vr[dt][c], bf.v, oo[dt], 0, 0, 0);
                ls = __builtin_amdgcn_mfma_f32_16x16x32_bf16(ones, bf.v, ls, 0, 0, 0);
            }
        };
        // wave-parity stagger (kept): wave 1 does subtile 1 first.
        if (w & 1) {
            phase(s1, o[1], lsB);
            phase(s0, o[0], lsA);
        } else {
            phase(s0, o[0], lsA);
            phase(s1, o[1], lsB);
        }
    }

#pragma unroll
    for (int qfi = 0; qfi < 2; qfi++) {
        float inv = 1.f / (qfi ? lsB[0] : lsA[0]);
        int tok = tokbase + qt * 64 + w * 32 + qfi * 16 + r16;
#pragma unroll
        for (int dt = 0; dt < 4; dt++) {
            union { unsigned int u[2]; us4 v; } pkv;
            pkv.u[0] = packbf(o[qfi][dt][0] * inv, o[qfi][dt][1] * inv);
            pkv.u[1] = packbf(o[qfi][dt][2] * inv, o[qfi][dt][3] * inv);
            *(us4*)(X + (size_t)tok * DIM + h * HD + dt * 16 + g * 4) = pkv.v;
        }
    }
}

extern "C" void kernel_launch(void* const* d_in, const int* in_sizes, int n_in,
                              void* d_out, int out_size, void* d_ws, size_t ws_size,
                              hipStream_t stream) {
    const float* query = (const float*)d_in[0];
    const float* key   = (const float*)d_in[1];
    const float* value = (const float*)d_in[2];
    const float* Wq    = (const float*)d_in[3];
    const float* Wk    = (const float*)d_in[4];
    const float* bk    = (const float*)d_in[5];
    const float* Wv    = (const float*)d_in[6];
    const float* Wp    = (const float*)d_in[7];
    const float* bp    = (const float*)d_in[8];
    float* out = (float*)d_out;

    unsigned short* ws = (unsigned short*)d_ws;
    unsigned short* Wqb = ws;
    unsigned short* Wkb = Wqb + WELEM;
    unsigned short* Wvb = Wkb + WELEM;
    unsigned short* Wpb = Wvb + WELEM;
    unsigned short* Qp  = Wpb + WELEM;
    unsigned short* Kp  = Qp + TELEM;
    unsigned short* Vtp = Kp + TELEM;
    unsigned short* Xp  = Vtp + TELEM;
    unsigned short* Qbf = Xp + TELEM;
    unsigned short* Kbf = Qbf + TELEM;
    unsigned short* Vbf = Kbf + TELEM;

    const size_t base_b = ((size_t)4 * WELEM + 4 * TELEM) * 2;
    const size_t cvt_b  = (size_t)3 * TELEM * 2;
    const bool cvt_ok = ws_size >= base_b + cvt_b;

    if (cvt_ok) {
        cvt_all<<<dim3((4 * WELEM + 3 * TELEM) / 8 / 256), 256, 0, stream>>>(
            Wq, Wk, Wv, Wp, query, key, value, Wqb, Qbf);
        qkv_gemm<1><<<dim3(64, 6, 3), 256, 0, stream>>>(Qbf, Kbf, Vbf, Wqb, Wkb, Wvb, bk, Qp, Kp, Vtp);
    } else {
        cvt_all<<<dim3(4 * WELEM / 8 / 256), 256, 0, stream>>>(
            Wq, Wk, Wv, Wp, query, key, value, Wqb, Qbf);
        qkv_gemm<0><<<dim3(64, 6, 3), 256, 0, stream>>>(query, key, value, Wqb, Wkb, Wvb, bk, Qp, Kp, Vtp);
    }
    attn_kernel<<<dim3(64, 24), 128, 0, stream>>>(Qp, Kp, Vtp, Xp);
    out_gemm<<<dim3(64, 6), 256, 0, stream>>>(Xp, Wpb, bp, out);
}

// Round 13
// 302.184 us; speedup vs baseline: 1.3080x; 1.1098x over previous
//
#include <hip/hip_runtime.h>
#include <hip/hip_bf16.h>

// Round 20: FULL REVERT to R17 (best measured: 304.2us). R18 (V-direct, 225us
// attn) and R19 (2-wave blocks, 165.9us attn: 4x staging per wave + 2x LDS
// write volume, occupancy 24->14%) both regressed. R17 config restored:
// - attn: 4 waves x 32 q-rows, 256 thr, lb(256,3), XCD swizzle (96/XCD),
//   QK-hoist, lsum-via-MFMA ones-trick, wave-parity stagger, K+V LDS dbuf.
// - GEMM: 128x128 BK=32 double-buffer (32KiB), XOR swizzle.
// - cvt_all fused converter.
// attn sits at MfmaUtil 41 + VALUBusy 57 ~= 98% combined issue saturation;
// exp VALU (irreducible) is the binding share. Structural levers exhausted
// (setprio x, 8/16-row waves x, V-direct x, 2-wave groups x, stagger ~0).

#define DIM 768
#define NH 12
#define HD 64
#define NTOK 4096
#define WELEM 589824u      // 768*768
#define TELEM 6291456u     // 2*4096*768

typedef short bf16x8 __attribute__((ext_vector_type(8)));
typedef float floatx4 __attribute__((ext_vector_type(4)));
typedef unsigned short us4 __attribute__((ext_vector_type(4)));

__device__ __forceinline__ float bf2f(unsigned short u) {
    union { unsigned int i; float f; } v; v.i = ((unsigned int)u) << 16; return v.f;
}
__device__ __forceinline__ unsigned short f2bf(float f) {
    union { float f; unsigned int i; } v; v.f = f;
    unsigned int r = v.i + 0x7fffu + ((v.i >> 16) & 1u);
    return (unsigned short)(r >> 16);
}
// pack 2 floats -> 2 bf16 in one VGPR (v_cvt_pk_bf16_f32 on gfx950)
__device__ __forceinline__ unsigned int packbf(float a, float b) {
    __hip_bfloat162 h = __float22bfloat162_rn(make_float2(a, b));
    union { __hip_bfloat162 h; unsigned int u; } cv; cv.h = h; return cv.u;
}
__device__ __forceinline__ void gl2lds16(const unsigned short* g, unsigned short* l) {
    __builtin_amdgcn_global_load_lds(
        (const __attribute__((address_space(1))) unsigned int*)g,
        (__attribute__((address_space(3))) unsigned int*)l, 16, 0, 0);
}
__device__ __forceinline__ bf16x8 ld8_f32_to_bf16(const float* p) {
    floatx4 f0 = *(const floatx4*)p;
    floatx4 f1 = *(const floatx4*)(p + 4);
    union { unsigned int u[4]; bf16x8 v; } o;
    o.u[0] = packbf(f0[0], f0[1]);
    o.u[1] = packbf(f0[2], f0[3]);
    o.u[2] = packbf(f1[0], f1[1]);
    o.u[3] = packbf(f1[2], f1[3]);
    return o.v;
}

#if __has_builtin(__builtin_amdgcn_exp2f)
#define EXPFN(x) __builtin_amdgcn_exp2f(x)
#define QSCALE 0.18033688011f   /* 0.125 * log2(e) */
#else
#define EXPFN(x) __expf(x)
#define QSCALE 0.125f
#endif

// ---------------- fused fp32 -> bf16 converter (weights + inputs) ----------
__global__ __launch_bounds__(256) void cvt_all(
    const float* __restrict__ Wq, const float* __restrict__ Wk,
    const float* __restrict__ Wv, const float* __restrict__ Wp,
    const float* __restrict__ q, const float* __restrict__ k,
    const float* __restrict__ v,
    unsigned short* __restrict__ wdst, unsigned short* __restrict__ idst)
{
    size_t i = ((size_t)blockIdx.x * 256 + threadIdx.x) * 8;
    const float* s; size_t off;
    if (i < 4u * WELEM) {
        if (i < WELEM)            { s = Wq; off = i; }
        else if (i < 2u * WELEM)  { s = Wk; off = i - WELEM; }
        else if (i < 3u * WELEM)  { s = Wv; off = i - 2u * WELEM; }
        else                      { s = Wp; off = i - 3u * WELEM; }
        *(bf16x8*)(wdst + i) = ld8_f32_to_bf16(s + off);
    } else {
        size_t j = i - 4u * WELEM;
        if (j < TELEM)            { s = q; off = j; }
        else if (j < 2u * TELEM)  { s = k; off = j - TELEM; }
        else                      { s = v; off = j - 2u * TELEM; }
        *(bf16x8*)(idst + j) = ld8_f32_to_bf16(s + off);
    }
}

// ---------------------------------------------------------------------------
// 128x128 tile GEMM, BK=32, double-buffered LDS (32KiB total).
// Row = 32 elems (64B) = 4 granules of 16B; XOR swizzle with (row>>1)&3.
// ---------------------------------------------------------------------------
template <int A_IS_BF16>
__device__ __forceinline__ void stage32(
    const void* __restrict__ Av, const unsigned short* __restrict__ W,
    unsigned short* Asb, unsigned short* Bsb,
    int m0, int n0, int k0, int w, int l)
{
    const int ro = l >> 2;   // 0..15
    const int gs = l & 3;    // LDS granule position
#pragma unroll
    for (int q = 0; q < 2; q++) {
        int rbase = w * 32 + q * 16;
        int row = rbase + ro;
        int col = ((gs ^ ((row >> 1) & 3)) * 8);   // pre-swizzled global source
        if (A_IS_BF16) {
            gl2lds16((const unsigned short*)Av + (size_t)(m0 + row) * DIM + k0 + col,
                     Asb + rbase * 32);
        } else {
            bf16x8 a = ld8_f32_to_bf16((const float*)Av + (size_t)(m0 + row) * DIM + k0 + col);
            *(bf16x8*)(Asb + row * 32 + gs * 8) = a;
        }
        gl2lds16(W + (size_t)(n0 + row) * DIM + k0 + col, Bsb + rbase * 32);
    }
}

template <int A_IS_BF16>
__device__ __forceinline__ void gemm128(
    const void* __restrict__ Av, const unsigned short* __restrict__ W,
    const float* __restrict__ bias, void* __restrict__ Cv,
    int has_bias, int do_gelu, int trans, int out_f32)
{
    __shared__ unsigned short As[2][128 * 32];
    __shared__ unsigned short Bs[2][128 * 32];
    const int m0 = blockIdx.x * 128, n0 = blockIdx.y * 128;
    const int tid = threadIdx.x;
    const int w = tid >> 6, l = tid & 63;
    const int g = l >> 4, r16 = l & 15;
    const int wm = w >> 1, wn = w & 1;
    const int NKT = DIM / 32;   // 24

    // fragment LDS offsets (swizzled read side)
    int aoff[4], boff[4];
#pragma unroll
    for (int i = 0; i < 4; i++) {
        int row = wm * 64 + i * 16 + r16;
        aoff[i] = row * 32 + ((g ^ ((row >> 1) & 3)) * 8);
    }
#pragma unroll
    for (int j = 0; j < 4; j++) {
        int row = wn * 64 + j * 16 + r16;
        boff[j] = row * 32 + ((g ^ ((row >> 1) & 3)) * 8);
    }

    floatx4 acc[4][4];
#pragma unroll
    for (int i = 0; i < 4; i++)
#pragma unroll
        for (int j = 0; j < 4; j++) acc[i][j] = (floatx4){0.f, 0.f, 0.f, 0.f};

    // prologue: stage tile 0 into buffer 0
    stage32<A_IS_BF16>(Av, W, As[0], Bs[0], m0, n0, 0, w, l);
    __syncthreads();

    for (int kt = 0; kt < NKT; kt++) {
        const int cur = kt & 1;

        // prefetch tile kt+1 into the other buffer (issued before compute)
        if (kt + 1 < NKT)
            stage32<A_IS_BF16>(Av, W, As[cur ^ 1], Bs[cur ^ 1],
                               m0, n0, (kt + 1) * 32, w, l);

        bf16x8 af[4], bfr[4];
#pragma unroll
        for (int i = 0; i < 4; i++)
            af[i] = *(const bf16x8*)(As[cur] + aoff[i]);
#pragma unroll
        for (int j = 0; j < 4; j++)
            bfr[j] = *(const bf16x8*)(Bs[cur] + boff[j]);
#pragma unroll
        for (int i = 0; i < 4; i++)
#pragma unroll
            for (int j = 0; j < 4; j++)
                acc[i][j] = __builtin_amdgcn_mfma_f32_16x16x32_bf16(af[i], bfr[j], acc[i][j], 0, 0, 0);

        // one barrier/iter: drains this iter's prefetch (issued ~compute-length
        // ago) and orders the buffer swap.
        __syncthreads();
    }

    if (trans) {
        unsigned short* C = (unsigned short*)Cv;
#pragma unroll
        for (int i = 0; i < 4; i++) {
            int m = m0 + wm * 64 + i * 16 + g * 4;
            int b = m >> 12, tloc = m & 4095;
#pragma unroll
            for (int j = 0; j < 4; j++) {
                int n = n0 + wn * 64 + j * 16 + r16;
                int h = n >> 6, d = n & 63;
                union { unsigned int u[2]; us4 v; } pk;
                pk.u[0] = packbf(acc[i][j][0], acc[i][j][1]);
                pk.u[1] = packbf(acc[i][j][2], acc[i][j][3]);
                *(us4*)(C + ((size_t)(b * NH + h) * 64 + d) * NTOK + tloc) = pk.v;
            }
        }
    } else {
#pragma unroll
        for (int i = 0; i < 4; i++)
#pragma unroll
            for (int j = 0; j < 4; j++) {
                int n = n0 + wn * 64 + j * 16 + r16;
                float bv = has_bias ? bias[n] : 0.f;
#pragma unroll
                for (int r = 0; r < 4; r++) {
                    int m = m0 + wm * 64 + i * 16 + g * 4 + r;
                    float v = acc[i][j][r] + bv;
                    if (do_gelu) v = 0.5f * v * (1.f + erff(v * 0.70710678118f));
                    if (out_f32) ((float*)Cv)[(size_t)m * DIM + n] = v;
                    else ((unsigned short*)Cv)[(size_t)m * DIM + n] = f2bf(v);
                }
            }
    }
}

template <int A_IS_BF16>
__global__ __launch_bounds__(256) void qkv_gemm(
    const void* __restrict__ q_in, const void* __restrict__ k_in,
    const void* __restrict__ v_in,
    const unsigned short* __restrict__ Wq, const unsigned short* __restrict__ Wk,
    const unsigned short* __restrict__ Wv, const float* __restrict__ bk,
    unsigned short* __restrict__ Qo, unsigned short* __restrict__ Ko,
    unsigned short* __restrict__ Vto)
{
    int z = blockIdx.z;
    const void* A = (z == 0) ? q_in : (z == 1) ? k_in : v_in;
    const unsigned short* W = (z == 0) ? Wq : (z == 1) ? Wk : Wv;
    unsigned short* C = (z == 0) ? Qo : (z == 1) ? Ko : Vto;
    gemm128<A_IS_BF16>(A, W, bk, C, z == 1, z == 1, z == 2, 0);
}

__global__ __launch_bounds__(256) void out_gemm(
    const unsigned short* __restrict__ X, const unsigned short* __restrict__ Wp,
    const float* __restrict__ bp, float* __restrict__ out)
{
    gemm128<1>(X, Wp, bp, out, 1, 0, 0, 1);
}

// ---------------------------------------------------------------------------
// Flash attention (R17 body): XCD swizzle, 4 waves x 32 q-rows, QK-hoist,
// lsum-via-MFMA ones-trick, wave-parity phase stagger, K+V LDS double-buffer.
// ---------------------------------------------------------------------------
__device__ __forceinline__ int swzf(int R) { return (R & 7) ^ ((R >> 2) & 6); }

__global__ __launch_bounds__(256, 3) void attn_kernel(
    const unsigned short* __restrict__ Q, const unsigned short* __restrict__ K,
    const unsigned short* __restrict__ Vt, unsigned short* __restrict__ X)
{
    __shared__ unsigned short Ks[2][64 * 64];
    __shared__ unsigned short Vs[2][64 * 64];
    // XCD swizzle: hw linear id -> logical id so each XCD (lid&7) owns 96
    // consecutive logical blocks = 3 full heads; K/V slab 3MB fits 4MB L2.
    const int lid = blockIdx.y * gridDim.x + blockIdx.x;   // 0..767
    const int lid2 = (lid & 7) * 96 + (lid >> 3);
    const int qt = lid2 & 31, bh = lid2 >> 5;
    const int b = bh / NH, h = bh % NH;
    const int tid = threadIdx.x;
    const int w = tid >> 6, l = tid & 63;
    const int g = l >> 4, r16 = l & 15;
    const int tokbase = b * NTOK;

    bf16x8 qfr[2][2];
#pragma unroll
    for (int qfi = 0; qfi < 2; qfi++) {
        int qrow = tokbase + qt * 128 + w * 32 + qfi * 16 + r16;
#pragma unroll
        for (int kk = 0; kk < 2; kk++) {
            bf16x8 t = *(const bf16x8*)(Q + (size_t)qrow * DIM + h * HD + kk * 32 + g * 8);
#pragma unroll
            for (int j = 0; j < 8; j++)
                t[j] = (short)f2bf(bf2f((unsigned short)t[j]) * QSCALE);
            qfr[qfi][kk] = t;
        }
    }

    bf16x8 ones;
#pragma unroll
    for (int j = 0; j < 8; j++) ones[j] = (short)0x3F80;

    int koff[4][2], voff[4][2];
#pragma unroll
    for (int ct = 0; ct < 4; ct++) {
        int krow = (ct >> 1) * 32 + (r16 >> 2) * 8 + (ct & 1) * 4 + (r16 & 3);
#pragma unroll
        for (int kk = 0; kk < 2; kk++)
            koff[ct][kk] = krow * 64 + (((kk * 4 + g) ^ swzf(krow)) * 8);
    }
#pragma unroll
    for (int dt = 0; dt < 4; dt++) {
        int vrow = dt * 16 + r16;
#pragma unroll
        for (int c = 0; c < 2; c++)
            voff[dt][c] = vrow * 64 + (((c * 4 + g) ^ swzf(vrow)) * 8);
    }

    // staging: waves 0,1 -> K (halves 0,1); waves 2,3 -> V (halves 0,1).
    const int kv = w >> 1, half = w & 1;
    int soff[4];
    const int srl = l >> 3, scc = l & 7;
    const int sstride = (kv == 0) ? DIM : NTOK;
#pragma unroll
    for (int i = 0; i < 4; i++) {
        int row = half * 32 + i * 8 + srl;
        soff[i] = row * sstride + ((scc ^ swzf(row)) * 8);
    }
    const unsigned short* Kbase = K + (size_t)tokbase * DIM + h * HD;
    const unsigned short* Vbase = Vt + (size_t)bh * 64 * NTOK;

    floatx4 o[2][4];
#pragma unroll
    for (int qfi = 0; qfi < 2; qfi++)
#pragma unroll
        for (int dt = 0; dt < 4; dt++) o[qfi][dt] = (floatx4){0.f, 0.f, 0.f, 0.f};
    floatx4 lsA = (floatx4){0.f, 0.f, 0.f, 0.f};
    floatx4 lsB = (floatx4){0.f, 0.f, 0.f, 0.f};

    // prologue: stage tile 0 into buffer 0
    {
        const unsigned short* p = (kv == 0) ? Kbase : Vbase;
        unsigned short* dst = ((kv == 0) ? Ks[0] : Vs[0]) + half * 2048;
#pragma unroll
        for (int i = 0; i < 4; i++) gl2lds16(p + soff[i], dst + i * 512);
    }

    for (int kt = 0; kt < NTOK / 64; kt++) {
        const int cur = kt & 1;
        __syncthreads();   // drains gl2lds -> tile kt visible to block

        bf16x8 kr[4][2], vr[4][2];
#pragma unroll
        for (int ct = 0; ct < 4; ct++)
#pragma unroll
            for (int kk = 0; kk < 2; kk++)
                kr[ct][kk] = *(const bf16x8*)(Ks[cur] + koff[ct][kk]);
#pragma unroll
        for (int dt = 0; dt < 4; dt++)
#pragma unroll
            for (int c = 0; c < 2; c++)
                vr[dt][c] = *(const bf16x8*)(Vs[cur] + voff[dt][c]);

        if (kt + 1 < NTOK / 64) {
            int keyg = (kt + 1) * 64;
            const unsigned short* p = (kv == 0) ? (Kbase + (size_t)keyg * DIM)
                                                : (Vbase + keyg);
            unsigned short* dst = ((kv == 0) ? Ks[cur ^ 1] : Vs[cur ^ 1]) + half * 2048;
#pragma unroll
            for (int i = 0; i < 4; i++) gl2lds16(p + soff[i], dst + i * 512);
        }

        // QK^T for BOTH q-subtiles up front (MFMAs retire under exp VALU).
        floatx4 s0[4], s1[4];
#pragma unroll
        for (int ct = 0; ct < 4; ct++) {
            floatx4 zz = (floatx4){0.f, 0.f, 0.f, 0.f};
            zz = __builtin_amdgcn_mfma_f32_16x16x32_bf16(kr[ct][0], qfr[0][0], zz, 0, 0, 0);
            s0[ct] = __builtin_amdgcn_mfma_f32_16x16x32_bf16(kr[ct][1], qfr[0][1], zz, 0, 0, 0);
        }
#pragma unroll
        for (int ct = 0; ct < 4; ct++) {
            floatx4 zz = (floatx4){0.f, 0.f, 0.f, 0.f};
            zz = __builtin_amdgcn_mfma_f32_16x16x32_bf16(kr[ct][0], qfr[1][0], zz, 0, 0, 0);
            s1[ct] = __builtin_amdgcn_mfma_f32_16x16x32_bf16(kr[ct][1], qfr[1][1], zz, 0, 0, 0);
        }

        auto phase = [&](floatx4* s, floatx4* oo, floatx4& ls) {
            unsigned int pk[4][2];
#pragma unroll
            for (int ct = 0; ct < 4; ct++) {
                float p0 = EXPFN(s[ct][0]);
                float p1 = EXPFN(s[ct][1]);
                float p2 = EXPFN(s[ct][2]);
                float p3 = EXPFN(s[ct][3]);
                pk[ct][0] = packbf(p0, p1);
                pk[ct][1] = packbf(p2, p3);
            }
#pragma unroll
            for (int c = 0; c < 2; c++) {
                union { unsigned int u[4]; bf16x8 v; } bf;
                bf.u[0] = pk[2 * c][0]; bf.u[1] = pk[2 * c][1];
                bf.u[2] = pk[2 * c + 1][0]; bf.u[3] = pk[2 * c + 1][1];
#pragma unroll
                for (int dt = 0; dt < 4; dt++)
                    oo[dt] = __builtin_amdgcn_mfma_f32_16x16x32_bf16(vr[dt][c], bf.v, oo[dt], 0, 0, 0);
                ls = __builtin_amdgcn_mfma_f32_16x16x32_bf16(ones, bf.v, ls, 0, 0, 0);
            }
        };
        // wave-parity stagger: odd waves do subtile 1 first.
        if (w & 1) {
            phase(s1, o[1], lsB);
            phase(s0, o[0], lsA);
        } else {
            phase(s0, o[0], lsA);
            phase(s1, o[1], lsB);
        }
    }

#pragma unroll
    for (int qfi = 0; qfi < 2; qfi++) {
        float inv = 1.f / (qfi ? lsB[0] : lsA[0]);
        int tok = tokbase + qt * 128 + w * 32 + qfi * 16 + r16;
#pragma unroll
        for (int dt = 0; dt < 4; dt++) {
            union { unsigned int u[2]; us4 v; } pkv;
            pkv.u[0] = packbf(o[qfi][dt][0] * inv, o[qfi][dt][1] * inv);
            pkv.u[1] = packbf(o[qfi][dt][2] * inv, o[qfi][dt][3] * inv);
            *(us4*)(X + (size_t)tok * DIM + h * HD + dt * 16 + g * 4) = pkv.v;
        }
    }
}

extern "C" void kernel_launch(void* const* d_in, const int* in_sizes, int n_in,
                              void* d_out, int out_size, void* d_ws, size_t ws_size,
                              hipStream_t stream) {
    const float* query = (const float*)d_in[0];
    const float* key   = (const float*)d_in[1];
    const float* value = (const float*)d_in[2];
    const float* Wq    = (const float*)d_in[3];
    const float* Wk    = (const float*)d_in[4];
    const float* bk    = (const float*)d_in[5];
    const float* Wv    = (const float*)d_in[6];
    const float* Wp    = (const float*)d_in[7];
    const float* bp    = (const float*)d_in[8];
    float* out = (float*)d_out;

    unsigned short* ws = (unsigned short*)d_ws;
    unsigned short* Wqb = ws;
    unsigned short* Wkb = Wqb + WELEM;
    unsigned short* Wvb = Wkb + WELEM;
    unsigned short* Wpb = Wvb + WELEM;
    unsigned short* Qp  = Wpb + WELEM;
    unsigned short* Kp  = Qp + TELEM;
    unsigned short* Vtp = Kp + TELEM;
    unsigned short* Xp  = Vtp + TELEM;
    unsigned short* Qbf = Xp + TELEM;
    unsigned short* Kbf = Qbf + TELEM;
    unsigned short* Vbf = Kbf + TELEM;

    const size_t base_b = ((size_t)4 * WELEM + 4 * TELEM) * 2;
    const size_t cvt_b  = (size_t)3 * TELEM * 2;
    const bool cvt_ok = ws_size >= base_b + cvt_b;

    if (cvt_ok) {
        cvt_all<<<dim3((4 * WELEM + 3 * TELEM) / 8 / 256), 256, 0, stream>>>(
            Wq, Wk, Wv, Wp, query, key, value, Wqb, Qbf);
        qkv_gemm<1><<<dim3(64, 6, 3), 256, 0, stream>>>(Qbf, Kbf, Vbf, Wqb, Wkb, Wvb, bk, Qp, Kp, Vtp);
    } else {
        cvt_all<<<dim3(4 * WELEM / 8 / 256), 256, 0, stream>>>(
            Wq, Wk, Wv, Wp, query, key, value, Wqb, Qbf);
        qkv_gemm<0><<<dim3(64, 6, 3), 256, 0, stream>>>(query, key, value, Wqb, Wkb, Wvb, bk, Qp, Kp, Vtp);
    }
    attn_kernel<<<dim3(32, 24), 256, 0, stream>>>(Qp, Kp, Vtp, Xp);
    out_gemm<<<dim3(64, 6), 256, 0, stream>>>(Xp, Wpb, bp, out);
}